// Round 1
// 435.717 us; speedup vs baseline: 1.0002x; 1.0002x over previous
//
#include <hip/hip_runtime.h>
#include <stdint.h>

typedef unsigned short u16;
typedef unsigned int   u32;
typedef __attribute__((ext_vector_type(8))) short    short8;  // 8 bf16 = 4 VGPRs
typedef __attribute__((ext_vector_type(8))) _Float16 half8;   // 8 fp16 = 4 VGPRs
typedef __attribute__((ext_vector_type(4))) _Float16 half4;
typedef __attribute__((ext_vector_type(4))) float    f32x4;

#define BB 2
#define SS 2048
#define EE 256
#define HH 8
#define DDh 32

// ---------- bf16 helpers ----------
__device__ __forceinline__ u16 f2b(float f){   // round-to-nearest-even
  union{u32 u; float f;} c; c.f = f;
  u32 r = c.u + 0x7fffu + ((c.u >> 16) & 1u);
  return (u16)(r >> 16);
}
__device__ __forceinline__ u32 pack2(float lo, float hi){
  return (u32)f2b(lo) | ((u32)f2b(hi) << 16);
}

// ---------- block reductions (256 threads = 4 waves of 64) ----------
__device__ __forceinline__ float blockSum(float v, float* red){
  #pragma unroll
  for (int off = 32; off > 0; off >>= 1) v += __shfl_xor(v, off, 64);
  int w = threadIdx.x >> 6;
  if ((threadIdx.x & 63) == 0) red[w] = v;
  __syncthreads();
  float r = (red[0] + red[1]) + (red[2] + red[3]);
  __syncthreads();
  return r;
}

// ---------- K-pre: fused LayerNorm + weight f32->fp16 convert ----------
// blocks [0, BB*SS)          : LN rows (one block per (b,s) row)
// blocks [BB*SS, BB*SS+320)  : Wq|Wk|Wv|Wg -> wcat, Wo -> woh
__global__ __launch_bounds__(256) void k_pre(const float* __restrict__ x,
    _Float16* __restrict__ xnh,
    const float* __restrict__ Wq, const float* __restrict__ Wk,
    const float* __restrict__ Wv, const float* __restrict__ Wg,
    const float* __restrict__ Wo,
    _Float16* __restrict__ wcat, _Float16* __restrict__ woh){
  __shared__ float red[4];
  int blk = blockIdx.x;
  if (blk < BB * SS){
    int t = threadIdx.x;
    float xv = x[(size_t)blk * EE + t];
    float s  = blockSum(xv, red);
    float ss = blockSum(xv * xv, red);
    float mean = s * (1.0f / EE);
    float var  = ss * (1.0f / EE) - mean * mean;
    float rstd = rsqrtf(var + 1e-5f);
    xnh[(size_t)blk * EE + t] = (_Float16)((xv - mean) * rstd);
  } else {
    int id = (blk - BB * SS) * 256 + threadIdx.x;   // 81920 = 5 * 16384
    int g = id >> 14, idx = id & 16383;
    const float* srcs[5] = {Wq, Wk, Wv, Wg, Wo};
    float4 v = ((const float4*)srcs[g])[idx];
    half4 h = {(_Float16)v.x, (_Float16)v.y, (_Float16)v.z, (_Float16)v.w};
    _Float16* dst = (g < 4) ? (wcat + (size_t)g * 65536) : woh;
    *(half4*)(dst + (size_t)idx * 4) = h;
  }
}

// ---------- K1: q/k/v/gate projection as one 4096x1024x256 fp16 MFMA GEMM.
__global__ __launch_bounds__(256) void k_proj(const _Float16* __restrict__ xnh,
    const _Float16* __restrict__ wcat, const float* __restrict__ bg,
    u16* __restrict__ qws, u16* __restrict__ kws,
    u16* __restrict__ vtws, float* __restrict__ gws){
  int t = threadIdx.x, wave = t >> 6, lane = t & 63;
  int q4 = lane >> 4, ln = lane & 15;
  int Mblk = blockIdx.x >> 4, Nblk = blockIdx.x & 15;
  int m0 = Mblk * 64, n0 = Nblk * 64 + wave * 16;
  int n = n0 + ln;
  const _Float16* brow = wcat + (size_t)n * EE;
  f32x4 acc[4];
  #pragma unroll
  for (int mb = 0; mb < 4; ++mb) acc[mb] = (f32x4){0.f,0.f,0.f,0.f};
  for (int k0 = 0; k0 < EE; k0 += 32){
    half8 bf = *(const half8*)(brow + k0 + q4 * 8);
    #pragma unroll
    for (int mb = 0; mb < 4; ++mb){
      half8 af = *(const half8*)(xnh + (size_t)(m0 + mb * 16 + ln) * EE + k0 + q4 * 8);
      acc[mb] = __builtin_amdgcn_mfma_f32_16x16x32_f16(af, bf, acc[mb], 0, 0, 0);
    }
  }
  int mat = n >> 8, c = n & 255;
  int h = c >> 5, d = c & 31;
  int b = m0 >> 11, s0 = (m0 & (SS - 1));
  size_t rowbase = ((size_t)b * HH + h) * SS;
  if (mat == 0){
    #pragma unroll
    for (int mb = 0; mb < 4; ++mb)
      #pragma unroll
      for (int r = 0; r < 4; ++r){
        int s = s0 + mb * 16 + q4 * 4 + r;
        qws[(rowbase + s) * DDh + d] = f2b(acc[mb][r] * 0.17677669529663687f);
      }
  } else if (mat == 1){
    #pragma unroll
    for (int mb = 0; mb < 4; ++mb)
      #pragma unroll
      for (int r = 0; r < 4; ++r){
        int s = s0 + mb * 16 + q4 * 4 + r;
        kws[(rowbase + s) * DDh + d] = f2b(acc[mb][r]);
      }
  } else if (mat == 2){
    u16* vrow = vtws + (((size_t)b * HH + h) * DDh + d) * SS;
    #pragma unroll
    for (int mb = 0; mb < 4; ++mb){
      ushort4 pk;
      pk.x = f2b(acc[mb][0]); pk.y = f2b(acc[mb][1]);
      pk.z = f2b(acc[mb][2]); pk.w = f2b(acc[mb][3]);
      *(ushort4*)(vrow + s0 + mb * 16 + q4 * 4) = pk;
    }
  } else {
    float bgv = bg[c];
    #pragma unroll
    for (int mb = 0; mb < 4; ++mb)
      #pragma unroll
      for (int r = 0; r < 4; ++r){
        int s = s0 + mb * 16 + q4 * 4 + r;
        gws[(rowbase + s) * DDh + d] = 1.0f / (1.0f + __expf(-(acc[mb][r] + bgv)));
      }
  }
}

// ---------- K2: flash attention, 64-wide j tiles, register double-buffer ----------
struct KTile {
  short8 ka0, ka1, ka2, ka3;   // K rows j0..j0+63, A-frags
  short8 va0, va1, va2, va3;   // V^T rows d(0..15)/(16..31), cols j0..j0+63
  float4 bv0, bv1, bv2, bv3;   // bias[i=ln][j0 + 16c + q4*4 .. +3]
};

__device__ __forceinline__ void tile_load(KTile& T, const u16* __restrict__ kb,
    const u16* __restrict__ vt, const float* __restrict__ br,
    int j0, int ln, int q4){
  T.ka0 = *(const short8*)(kb + (size_t)(j0      + ln) * DDh + q4 * 8);
  T.ka1 = *(const short8*)(kb + (size_t)(j0 + 16 + ln) * DDh + q4 * 8);
  T.ka2 = *(const short8*)(kb + (size_t)(j0 + 32 + ln) * DDh + q4 * 8);
  T.ka3 = *(const short8*)(kb + (size_t)(j0 + 48 + ln) * DDh + q4 * 8);
  T.va0 = *(const short8*)(vt + (size_t)ln        * SS + j0      + q4 * 8);
  T.va1 = *(const short8*)(vt + (size_t)ln        * SS + j0 + 32 + q4 * 8);
  T.va2 = *(const short8*)(vt + (size_t)(16 + ln) * SS + j0      + q4 * 8);
  T.va3 = *(const short8*)(vt + (size_t)(16 + ln) * SS + j0 + 32 + q4 * 8);
  const float* b0 = br + (size_t)ln * SS + j0 + q4 * 4;
  T.bv0 = *(const float4*)(b0);
  T.bv1 = *(const float4*)(b0 + 16);
  T.bv2 = *(const float4*)(b0 + 32);
  T.bv3 = *(const float4*)(b0 + 48);
}

// transpose 8 P values (2 j-16-tiles in C-layout) into one PV B-frag
__device__ __forceinline__ short8 ptrans(const float* p, int sl, int sl2, bool lo){
  u32 P0 = pack2(p[0], p[1]), P1 = pack2(p[2], p[3]);
  u32 P2 = pack2(p[4], p[5]), P3 = pack2(p[6], p[7]);
  u32 x0 = __shfl((int)P0, sl,  64), x1 = __shfl((int)P1, sl,  64);
  u32 x2 = __shfl((int)P2, sl,  64), x3 = __shfl((int)P3, sl,  64);
  u32 y0 = __shfl((int)P0, sl2, 64), y1 = __shfl((int)P1, sl2, 64);
  u32 y2 = __shfl((int)P2, sl2, 64), y3 = __shfl((int)P3, sl2, 64);
  u32 bb[4];
  bb[0] = lo ? x0 : x2;  bb[1] = lo ? x1 : x3;
  bb[2] = lo ? y0 : y2;  bb[3] = lo ? y1 : y3;
  return *(short8*)bb;
}

__device__ __forceinline__ void tile_compute(const KTile& T,
    const float* __restrict__ mrow, int j0, short8 qf,
    int q4, int sl, int sl2, bool lo,
    f32x4& O0, f32x4& O1, float& m_run, float& l_run){
  const f32x4 zero = {0.f,0.f,0.f,0.f};
  float4 mv0 = *(const float4*)(mrow + j0      + q4 * 4);
  float4 mv1 = *(const float4*)(mrow + j0 + 16 + q4 * 4);
  float4 mv2 = *(const float4*)(mrow + j0 + 32 + q4 * 4);
  float4 mv3 = *(const float4*)(mrow + j0 + 48 + q4 * 4);

  f32x4 s0 = __builtin_amdgcn_mfma_f32_16x16x32_bf16(T.ka0, qf, zero, 0, 0, 0);
  f32x4 s1 = __builtin_amdgcn_mfma_f32_16x16x32_bf16(T.ka1, qf, zero, 0, 0, 0);
  f32x4 s2 = __builtin_amdgcn_mfma_f32_16x16x32_bf16(T.ka2, qf, zero, 0, 0, 0);
  f32x4 s3 = __builtin_amdgcn_mfma_f32_16x16x32_bf16(T.ka3, qf, zero, 0, 0, 0);

  float lg[16];
  lg[0]  = (mv0.x >= 0.5f) ? s0[0] + T.bv0.x : -32768.0f;
  lg[1]  = (mv0.y >= 0.5f) ? s0[1] + T.bv0.y : -32768.0f;
  lg[2]  = (mv0.z >= 0.5f) ? s0[2] + T.bv0.z : -32768.0f;
  lg[3]  = (mv0.w >= 0.5f) ? s0[3] + T.bv0.w : -32768.0f;
  lg[4]  = (mv1.x >= 0.5f) ? s1[0] + T.bv1.x : -32768.0f;
  lg[5]  = (mv1.y >= 0.5f) ? s1[1] + T.bv1.y : -32768.0f;
  lg[6]  = (mv1.z >= 0.5f) ? s1[2] + T.bv1.z : -32768.0f;
  lg[7]  = (mv1.w >= 0.5f) ? s1[3] + T.bv1.w : -32768.0f;
  lg[8]  = (mv2.x >= 0.5f) ? s2[0] + T.bv2.x : -32768.0f;
  lg[9]  = (mv2.y >= 0.5f) ? s2[1] + T.bv2.y : -32768.0f;
  lg[10] = (mv2.z >= 0.5f) ? s2[2] + T.bv2.z : -32768.0f;
  lg[11] = (mv2.w >= 0.5f) ? s2[3] + T.bv2.w : -32768.0f;
  lg[12] = (mv3.x >= 0.5f) ? s3[0] + T.bv3.x : -32768.0f;
  lg[13] = (mv3.y >= 0.5f) ? s3[1] + T.bv3.y : -32768.0f;
  lg[14] = (mv3.z >= 0.5f) ? s3[2] + T.bv3.z : -32768.0f;
  lg[15] = (mv3.w >= 0.5f) ? s3[3] + T.bv3.w : -32768.0f;

  float ma = fmaxf(fmaxf(lg[0], lg[1]),  fmaxf(lg[2],  lg[3]));
  float mb = fmaxf(fmaxf(lg[4], lg[5]),  fmaxf(lg[6],  lg[7]));
  float mc = fmaxf(fmaxf(lg[8], lg[9]),  fmaxf(lg[10], lg[11]));
  float md = fmaxf(fmaxf(lg[12],lg[13]), fmaxf(lg[14], lg[15]));
  float mt = fmaxf(fmaxf(ma, mb), fmaxf(mc, md));
  mt = fmaxf(mt, __shfl_xor(mt, 16, 64));
  mt = fmaxf(mt, __shfl_xor(mt, 32, 64));
  float m_new = fmaxf(m_run, mt);
  float alpha = __expf(m_run - m_new);

  float p[16];
  #pragma unroll
  for (int r = 0; r < 16; ++r) p[r] = __expf(lg[r] - m_new);
  float ts = (((p[0]+p[1])+(p[2]+p[3])) + ((p[4]+p[5])+(p[6]+p[7])))
           + (((p[8]+p[9])+(p[10]+p[11])) + ((p[12]+p[13])+(p[14]+p[15])));
  ts += __shfl_xor(ts, 16, 64);
  ts += __shfl_xor(ts, 32, 64);
  l_run = l_run * alpha + ts;
  m_run = m_new;
  #pragma unroll
  for (int e = 0; e < 4; ++e){ O0[e] *= alpha; O1[e] *= alpha; }

  short8 pfA = ptrans(p,     sl, sl2, lo);   // cols j0   .. j0+31
  short8 pfB = ptrans(p + 8, sl, sl2, lo);   // cols j0+32.. j0+63

  __builtin_amdgcn_s_setprio(1);
  O0 = __builtin_amdgcn_mfma_f32_16x16x32_bf16(T.va0, pfA, O0, 0, 0, 0);
  O0 = __builtin_amdgcn_mfma_f32_16x16x32_bf16(T.va1, pfB, O0, 0, 0, 0);
  O1 = __builtin_amdgcn_mfma_f32_16x16x32_bf16(T.va2, pfA, O1, 0, 0, 0);
  O1 = __builtin_amdgcn_mfma_f32_16x16x32_bf16(T.va3, pfB, O1, 0, 0, 0);
  __builtin_amdgcn_s_setprio(0);
}

__global__ __launch_bounds__(256, 2) void k_attn(const u16* __restrict__ qws,
    const u16* __restrict__ kws, const u16* __restrict__ vtws,
    const float* __restrict__ gws, const float* __restrict__ bias,
    const float* __restrict__ mask, _Float16* __restrict__ gouth){
  int t = threadIdx.x;
  int wave = t >> 6, lane = t & 63;
  int q4 = lane >> 4, ln = lane & 15;
  int bh = blockIdx.x >> 5;
  int i0 = (blockIdx.x & 31) * 64 + wave * 16;
  int b = bh >> 3, h = bh & 7;
  int sl  = (q4 & 1) * 32 + ln;
  int sl2 = sl + 16;
  bool lo = (q4 < 2);

  short8 qf = *(const short8*)(qws + (((size_t)bh * SS + i0 + ln) * DDh) + q4 * 8);
  const u16*  kb   = kws  + (size_t)bh * SS * DDh;
  const u16*  vt   = vtws + (size_t)bh * DDh * SS;
  const float* br  = bias + ((size_t)bh * SS + i0) * SS;
  const float* mrow= mask + (size_t)b * SS;

  f32x4 O0 = {0.f,0.f,0.f,0.f}, O1 = {0.f,0.f,0.f,0.f};
  float m_run = -INFINITY, l_run = 0.0f;

  KTile A, Bt;
  tile_load(A, kb, vt, br, 0, ln, q4);
  for (int j0 = 0; j0 < SS; j0 += 128){
    tile_load(Bt, kb, vt, br, j0 + 64, ln, q4);
    tile_compute(A, mrow, j0, qf, q4, sl, sl2, lo, O0, O1, m_run, l_run);
    if (j0 + 128 < SS)
      tile_load(A, kb, vt, br, j0 + 128, ln, q4);
    tile_compute(Bt, mrow, j0 + 64, qf, q4, sl, sl2, lo, O0, O1, m_run, l_run);
  }

  float inv = 1.0f / l_run;
  const float* gr = gws + ((size_t)bh * SS + i0 + ln) * DDh;
  float4 g0 = *(const float4*)(gr + q4 * 4);
  float4 g1 = *(const float4*)(gr + 16 + q4 * 4);
  _Float16* orow = gouth + ((size_t)b * SS + (i0 + ln)) * EE + h * DDh;
  half4 w0, w1;
  w0.x = (_Float16)(O0[0] * inv * g0.x);  w0.y = (_Float16)(O0[1] * inv * g0.y);
  w0.z = (_Float16)(O0[2] * inv * g0.z);  w0.w = (_Float16)(O0[3] * inv * g0.w);
  w1.x = (_Float16)(O1[0] * inv * g1.x);  w1.y = (_Float16)(O1[1] * inv * g1.y);
  w1.z = (_Float16)(O1[2] * inv * g1.z);  w1.w = (_Float16)(O1[3] * inv * g1.w);
  *(half4*)(orow + q4 * 4)      = w0;
  *(half4*)(orow + 16 + q4 * 4) = w1;
}

// ---------- K3: output projection as 4096x256x256 fp16 MFMA GEMM ----------
__global__ __launch_bounds__(256) void k_out(const _Float16* __restrict__ gouth,
    const _Float16* __restrict__ woh, const float* __restrict__ bo,
    float* __restrict__ out){
  int t = threadIdx.x, wave = t >> 6, lane = t & 63;
  int q4 = lane >> 4, ln = lane & 15;
  int Mblk = blockIdx.x >> 2, Nblk = blockIdx.x & 3;
  int m0 = Mblk * 64, n0 = Nblk * 64 + wave * 16;
  int n = n0 + ln;
  const _Float16* brow = woh + (size_t)n * EE;
  f32x4 acc[4];
  #pragma unroll
  for (int mb = 0; mb < 4; ++mb) acc[mb] = (f32x4){0.f,0.f,0.f,0.f};
  for (int k0 = 0; k0 < EE; k0 += 32){
    half8 bf = *(const half8*)(brow + k0 + q4 * 8);
    #pragma unroll
    for (int mb = 0; mb < 4; ++mb){
      half8 af = *(const half8*)(gouth + (size_t)(m0 + mb * 16 + ln) * EE + k0 + q4 * 8);
      acc[mb] = __builtin_amdgcn_mfma_f32_16x16x32_f16(af, bf, acc[mb], 0, 0, 0);
    }
  }
  float bov = bo[n];
  #pragma unroll
  for (int mb = 0; mb < 4; ++mb)
    #pragma unroll
    for (int r = 0; r < 4; ++r){
      int m = m0 + mb * 16 + q4 * 4 + r;
      out[(size_t)m * EE + n] = acc[mb][r] + bov;
    }
}

extern "C" void kernel_launch(void* const* d_in, const int* in_sizes, int n_in,
                              void* d_out, int out_size, void* d_ws, size_t ws_size,
                              hipStream_t stream){
  const float* x    = (const float*)d_in[0];
  const float* mask = (const float*)d_in[1];
  const float* bias = (const float*)d_in[2];
  const float* Wq   = (const float*)d_in[3];
  const float* Wk   = (const float*)d_in[4];
  const float* Wv   = (const float*)d_in[5];
  const float* Wg   = (const float*)d_in[6];
  const float* bg   = (const float*)d_in[7];
  const float* Wo   = (const float*)d_in[8];
  const float* bo   = (const float*)d_in[9];
  float* out = (float*)d_out;

  char* ws = (char*)d_ws;
  _Float16* xnh  = (_Float16*)ws;                // 2 MB  [4096][256] fp16 LN(x)
  u16*  qws  = (u16*) (ws + (2  << 20));         // 2 MB  [bh][S][32] bf16, pre-scaled
  u16*  kws  = (u16*) (ws + (4  << 20));         // 2 MB  [bh][S][32] bf16
  u16*  vtws = (u16*) (ws + (6  << 20));         // 2 MB  [bh][32][S] bf16 (transposed)
  float* gws = (float*)(ws + (8  << 20));        // 4 MB  [bh][S][32] f32 sigmoid gate
  _Float16* gouth = (_Float16*)(ws + (12 << 20));// 2 MB  [b][S][256] fp16 gated attn out
  _Float16* wcat  = (_Float16*)(ws + (14 << 20));// 512K  [1024][256] fp16 Wq|Wk|Wv|Wg
  _Float16* woh   = (_Float16*)(ws + (15 << 20));// 128K  [256][256] fp16 Wo

  hipLaunchKernelGGL(k_pre,  dim3(BB * SS + 320),      dim3(256), 0, stream,
                     x, xnh, Wq, Wk, Wv, Wg, Wo, wcat, woh);
  hipLaunchKernelGGL(k_proj, dim3(64 * 16),            dim3(256), 0, stream,
                     xnh, wcat, bg, qws, kws, vtws, gws);
  hipLaunchKernelGGL(k_attn, dim3(BB * HH * (SS / 64)), dim3(256), 0, stream,
                     qws, kws, vtws, gws, bias, mask, gouth);
  hipLaunchKernelGGL(k_out,  dim3(64 * 4),             dim3(256), 0, stream,
                     gouth, woh, bo, out);
}